// Round 1
// baseline (3123.172 us; speedup 1.0000x reference)
//
#include <hip/hip_runtime.h>
#include <hip/hip_bf16.h>

#define T_LEN 2048
#define BATCH 32
#define HDIM 256
#define H3 768
#define EMBD 63
#define NSING 1024

typedef _Float16 half2_t __attribute__((ext_vector_type(2)));

__device__ __forceinline__ float fdot2u(unsigned int a, unsigned int b, float c) {
#if __has_builtin(__builtin_amdgcn_fdot2)
  return __builtin_amdgcn_fdot2(__builtin_bit_cast(half2_t, a),
                                __builtin_bit_cast(half2_t, b), c, false);
#else
  half2_t ha = __builtin_bit_cast(half2_t, a);
  half2_t hb = __builtin_bit_cast(half2_t, b);
  return c + (float)ha.x * (float)hb.x + (float)ha.y * (float)hb.y;
#endif
}

// P[s][j] = bi[j] + sum_e embed[s,e] * Wi[(1+e),j]   (input-gate GEMM folded per singer)
__global__ __launch_bounds__(768) void precompute_P(
    const float* __restrict__ embed, const float* __restrict__ Wi,
    const float* __restrict__ bi, float* __restrict__ P) {
  const int s = blockIdx.x;
  const int j = threadIdx.x;
  float acc = bi[j];
  const float* er = embed + s * EMBD;
#pragma unroll
  for (int e = 0; e < EMBD; e++) acc += er[e] * Wi[(e + 1) * H3 + j];
  P[s * H3 + j] = acc;
}

// One workgroup per (dir, batch). 768 threads; thread j owns Wh column j in
// 128 packed-f16 VGPRs. h kept in LDS as packed f16 (broadcast reads).
__global__ __launch_bounds__(768, 3) void gru_scan(
    const float* __restrict__ dur, const int* __restrict__ sid,
    const float* __restrict__ Wh_f, const float* __restrict__ Wh_b,
    const float* __restrict__ Wi_f, const float* __restrict__ Wi_b,
    const float* __restrict__ bhn_f, const float* __restrict__ bhn_b,
    const float* __restrict__ Wd,
    const float* __restrict__ Pf, const float* __restrict__ Pb,
    float* __restrict__ partial) {
  const int b = blockIdx.x & 31;
  const int dir = blockIdx.x >> 5;
  const int j = threadIdx.x;

  const float* __restrict__ Wh = dir ? Wh_b : Wh_f;
  const float* __restrict__ Wi = dir ? Wi_b : Wi_f;
  const float* __restrict__ P = dir ? Pb : Pf;
  const float* __restrict__ bhn = dir ? bhn_b : bhn_f;

  __shared__ __align__(16) unsigned int h2buf[HDIM / 2];  // packed f16 h (128 dwords)
  __shared__ float glds[H3];  // [0:256) z, [256:512) hn+bhn, [512:768) inn
  __shared__ float red[4];

  // Load Wh column j, pack to f16 pairs (k ascending). 128 VGPRs, persistent.
  unsigned int w[128];
#pragma unroll
  for (int k = 0; k < 128; k++) {
    float x0 = Wh[(2 * k) * H3 + j];
    float x1 = Wh[(2 * k + 1) * H3 + j];
    half2_t hp;
    hp.x = (_Float16)x0;
    hp.y = (_Float16)x1;
    w[k] = __builtin_bit_cast(unsigned int, hp);
  }
  const float wi0 = Wi[j];                                   // duration weight
  const float wd = (j < HDIM) ? Wd[dir * HDIM + j] : 0.f;    // output head slice
  const float bhnj = (j >= 2 * HDIM) ? bhn[j - 2 * HDIM] : 0.f;

  if (j < HDIM / 2) h2buf[j] = 0u;
  float h_prev = 0.f;

  const float* durb = dur + b * T_LEN;
  const int* sidb = sid + b * T_LEN;
  float* pout = partial + ((size_t)dir * BATCH + b) * T_LEN;

  // software-pipelined prefetch: sid/dur 2 steps ahead, P row 1 step ahead
  const int tt0 = dir ? (T_LEN - 1) : 0;
  const int tt1 = dir ? (T_LEN - 2) : 1;
  float dur_c = durb[tt0];
  float dur_n = durb[tt1];
  int sid_n = sidb[tt1];
  float p_c = P[sidb[tt0] * H3 + j];
  __syncthreads();

  for (int t = 0; t < T_LEN; t++) {
    const int t2 = (t + 2 < T_LEN) ? (t + 2) : (T_LEN - 1);
    const int tt2 = dir ? (T_LEN - 1 - t2) : t2;
    const int sid2 = sidb[tt2];
    const float dur2 = durb[tt2];
    const float p_n = P[sid_n * H3 + j];

    // gh[j] = sum_k h[k] * Wh[k][j]  -- 128 x v_dot2_f32_f16
    float a0 = 0.f, a1 = 0.f, a2 = 0.f, a3 = 0.f;
#pragma unroll
    for (int k = 0; k < 32; k++) {
      uint4 hv = ((const uint4*)h2buf)[k];
      a0 = fdot2u(hv.x, w[4 * k + 0], a0);
      a1 = fdot2u(hv.y, w[4 * k + 1], a1);
      a2 = fdot2u(hv.z, w[4 * k + 2], a2);
      a3 = fdot2u(hv.w, w[4 * k + 3], a3);
    }
    const float gh = (a0 + a1) + (a2 + a3);
    const float gi = p_c + dur_c * wi0;  // input gate contribution (P gather + dur FMA)

    if (j >= 2 * HDIM) {
      glds[j - HDIM] = gh + bhnj;  // hn + bhn
      glds[j] = gi;                // inn (kept separate: r multiplies only hn+bhn)
    } else if (j >= HDIM) {
      const float x = gh + gi;
      glds[j - HDIM] = 1.f / (1.f + __expf(-x));  // z computed by owning thread
    }
    __syncthreads();

    if (j < HDIM) {
      const float x = gh + gi;
      const float r = 1.f / (1.f + __expf(-x));
      const float z = glds[j];
      const float nin = glds[2 * HDIM + j] + r * glds[HDIM + j];
      const float n = 1.f - 2.f / (1.f + __expf(2.f * nin));  // tanh(nin), overflow-safe
      const float h_new = n + z * (h_prev - n);
      h_prev = h_new;
      ((unsigned short*)h2buf)[j] =
          __builtin_bit_cast(unsigned short, (_Float16)h_new);
      // fused output head: pd = h_new * Wd[j], wave-reduce
      float pd = h_new * wd;
#pragma unroll
      for (int off = 32; off >= 1; off >>= 1) pd += __shfl_down(pd, off, 64);
      if ((j & 63) == 0) red[j >> 6] = pd;
    }
    __syncthreads();
    if (j == 0)
      pout[dir ? (T_LEN - 1 - t) : t] = (red[0] + red[1]) + (red[2] + red[3]);

    p_c = p_n;
    sid_n = sid2;
    dur_c = dur_n;
    dur_n = dur2;
  }
}

__global__ void combine(const float* __restrict__ pf, const float* __restrict__ pb,
                        const float* __restrict__ bd, float* __restrict__ out) {
  const int i = blockIdx.x * blockDim.x + threadIdx.x;
  out[i] = pf[i] + pb[i] + bd[0];
}

extern "C" void kernel_launch(void* const* d_in, const int* in_sizes, int n_in,
                              void* d_out, int out_size, void* d_ws, size_t ws_size,
                              hipStream_t stream) {
  const float* dur = (const float*)d_in[0];
  const int* sid = (const int*)d_in[1];
  const float* embed = (const float*)d_in[2];
  const float* Wi_f = (const float*)d_in[3];
  const float* Wh_f = (const float*)d_in[4];
  const float* bi_f = (const float*)d_in[5];
  const float* bhn_f = (const float*)d_in[6];
  const float* Wi_b = (const float*)d_in[7];
  const float* Wh_b = (const float*)d_in[8];
  const float* bi_b = (const float*)d_in[9];
  const float* bhn_b = (const float*)d_in[10];
  const float* Wd = (const float*)d_in[11];
  const float* bd = (const float*)d_in[12];
  float* out = (float*)d_out;

  // ws layout (floats): [0,65536) fwd partial, [65536,131072) bwd partial,
  // then Pf (1024*768), then Pb (1024*768). Total ~6.8 MB.
  float* ws = (float*)d_ws;
  float* pf = ws;
  float* pb = ws + 65536;
  float* Pf = ws + 131072;
  float* Pb = Pf + NSING * H3;

  hipLaunchKernelGGL(precompute_P, dim3(NSING), dim3(H3), 0, stream, embed, Wi_f, bi_f, Pf);
  hipLaunchKernelGGL(precompute_P, dim3(NSING), dim3(H3), 0, stream, embed, Wi_b, bi_b, Pb);
  hipLaunchKernelGGL(gru_scan, dim3(64), dim3(H3), 0, stream,
                     dur, sid, Wh_f, Wh_b, Wi_f, Wi_b, bhn_f, bhn_b, Wd, Pf, Pb, ws);
  hipLaunchKernelGGL(combine, dim3(out_size / 256), dim3(256), 0, stream, pf, pb, bd, out);
}

// Round 2
// 3066.217 us; speedup vs baseline: 1.0186x; 1.0186x over previous
//
#include <hip/hip_runtime.h>
#include <hip/hip_bf16.h>

#define T_LEN 2048
#define BATCH 32
#define HDIM 256
#define H3 768
#define EMBD 63
#define NSING 1024

typedef _Float16 half2_t __attribute__((ext_vector_type(2)));

__device__ __forceinline__ float fdot2u(unsigned int a, unsigned int b, float c) {
#if __has_builtin(__builtin_amdgcn_fdot2)
  return __builtin_amdgcn_fdot2(__builtin_bit_cast(half2_t, a),
                                __builtin_bit_cast(half2_t, b), c, false);
#else
  half2_t ha = __builtin_bit_cast(half2_t, a);
  half2_t hb = __builtin_bit_cast(half2_t, b);
  return c + (float)ha.x * (float)hb.x + (float)ha.y * (float)hb.y;
#endif
}

// P[s][j] = bi[j] + sum_e embed[s,e] * Wi[(1+e),j]   (input-gate GEMM folded per singer)
__global__ __launch_bounds__(768) void precompute_P(
    const float* __restrict__ embed, const float* __restrict__ Wi,
    const float* __restrict__ bi, float* __restrict__ P) {
  const int s = blockIdx.x;
  const int j = threadIdx.x;
  float acc = bi[j];
  const float* er = embed + s * EMBD;
#pragma unroll
  for (int e = 0; e < EMBD; e++) acc += er[e] * Wi[(e + 1) * H3 + j];
  P[s * H3 + j] = acc;
}

// Pack Wh (f32 [256][768]) into f16-pair dwords: Whp[(dir*128+k)*768+j] =
// pack(Wh[2k][j], Wh[2k+1][j]).  Scan then loads 128 coalesced dwords/thread.
__global__ __launch_bounds__(768) void pack_Wh(
    const float* __restrict__ Wh_f, const float* __restrict__ Wh_b,
    unsigned int* __restrict__ Whp) {
  const int k = blockIdx.x & 127;
  const int d = blockIdx.x >> 7;
  const int j = threadIdx.x;
  const float* Wh = d ? Wh_b : Wh_f;
  half2_t hp;
  hp.x = (_Float16)Wh[(2 * k) * H3 + j];
  hp.y = (_Float16)Wh[(2 * k + 1) * H3 + j];
  Whp[((size_t)(d * 128 + k)) * H3 + j] = __builtin_bit_cast(unsigned int, hp);
}

// One workgroup per (dir, batch). 768 threads; thread j owns Wh column j in
// 128 packed-f16 VGPRs. h kept in LDS as packed f16 (broadcast reads).
// waves_per_eu(3,3): pin occupancy so the allocator gets the full 170-VGPR
// budget — without the max=3, it squeezed to the 6-wave tier (85 VGPR) and
// spilled w[] to scratch (round-1: VGPR_Count=84, 3.4x slowdown).
__global__ __launch_bounds__(768)
__attribute__((amdgpu_waves_per_eu(3, 3))) void gru_scan(
    const float* __restrict__ dur, const int* __restrict__ sid,
    const unsigned int* __restrict__ Whp,
    const float* __restrict__ Wi_f, const float* __restrict__ Wi_b,
    const float* __restrict__ bhn_f, const float* __restrict__ bhn_b,
    const float* __restrict__ Wd,
    const float* __restrict__ Pf, const float* __restrict__ Pb,
    float* __restrict__ partial) {
  const int b = blockIdx.x & 31;
  const int dir = blockIdx.x >> 5;
  const int j = threadIdx.x;

  const float* __restrict__ Wi = dir ? Wi_b : Wi_f;
  const float* __restrict__ P = dir ? Pb : Pf;
  const float* __restrict__ bhn = dir ? bhn_b : bhn_f;

  __shared__ __align__(16) unsigned int h2buf[HDIM / 2];  // packed f16 h (128 dwords)
  __shared__ float glds[H3];  // [0:256) z, [256:512) hn+bhn, [512:768) inn
  __shared__ float red[4];

  // Load packed Wh column j: 128 coalesced dword loads, persistent in VGPRs.
  unsigned int w[128];
  {
    const unsigned int* wrow = Whp + (size_t)dir * 128 * H3 + j;
#pragma unroll
    for (int k = 0; k < 128; k++) w[k] = wrow[k * H3];
  }
  const float wi0 = Wi[j];                                   // duration weight
  const float wd = (j < HDIM) ? Wd[dir * HDIM + j] : 0.f;    // output head slice
  const float bhnj = (j >= 2 * HDIM) ? bhn[j - 2 * HDIM] : 0.f;

  if (j < HDIM / 2) h2buf[j] = 0u;
  float h_prev = 0.f;

  const float* durb = dur + b * T_LEN;
  const int* sidb = sid + b * T_LEN;
  float* pout = partial + ((size_t)dir * BATCH + b) * T_LEN;

  // software-pipelined prefetch: sid/dur 2 steps ahead, P row 1 step ahead
  const int tt0 = dir ? (T_LEN - 1) : 0;
  const int tt1 = dir ? (T_LEN - 2) : 1;
  float dur_c = durb[tt0];
  float dur_n = durb[tt1];
  int sid_n = sidb[tt1];
  float p_c = P[sidb[tt0] * H3 + j];
  __syncthreads();

  for (int t = 0; t < T_LEN; t++) {
    const int t2 = (t + 2 < T_LEN) ? (t + 2) : (T_LEN - 1);
    const int tt2 = dir ? (T_LEN - 1 - t2) : t2;
    const int sid2 = sidb[tt2];
    const float dur2 = durb[tt2];
    const float p_n = P[sid_n * H3 + j];

    // gh[j] = sum_k h[k] * Wh[k][j]  -- 128 x v_dot2_f32_f16
    float a0 = 0.f, a1 = 0.f, a2 = 0.f, a3 = 0.f;
#pragma unroll
    for (int k = 0; k < 32; k++) {
      uint4 hv = ((const uint4*)h2buf)[k];
      a0 = fdot2u(hv.x, w[4 * k + 0], a0);
      a1 = fdot2u(hv.y, w[4 * k + 1], a1);
      a2 = fdot2u(hv.z, w[4 * k + 2], a2);
      a3 = fdot2u(hv.w, w[4 * k + 3], a3);
    }
    const float gh = (a0 + a1) + (a2 + a3);
    const float gi = p_c + dur_c * wi0;  // input gate contribution (P gather + dur FMA)

    if (j >= 2 * HDIM) {
      glds[j - HDIM] = gh + bhnj;  // hn + bhn
      glds[j] = gi;                // inn (kept separate: r multiplies only hn+bhn)
    } else if (j >= HDIM) {
      const float x = gh + gi;
      glds[j - HDIM] = 1.f / (1.f + __expf(-x));  // z computed by owning thread
    }
    __syncthreads();

    if (j < HDIM) {
      const float x = gh + gi;
      const float r = 1.f / (1.f + __expf(-x));
      const float z = glds[j];
      const float nin = glds[2 * HDIM + j] + r * glds[HDIM + j];
      const float n = 1.f - 2.f / (1.f + __expf(2.f * nin));  // tanh(nin), overflow-safe
      const float h_new = n + z * (h_prev - n);
      h_prev = h_new;
      ((unsigned short*)h2buf)[j] =
          __builtin_bit_cast(unsigned short, (_Float16)h_new);
      // fused output head: pd = h_new * Wd[j], wave-reduce
      float pd = h_new * wd;
#pragma unroll
      for (int off = 32; off >= 1; off >>= 1) pd += __shfl_down(pd, off, 64);
      if ((j & 63) == 0) red[j >> 6] = pd;
    }
    __syncthreads();
    if (j == 0)
      pout[dir ? (T_LEN - 1 - t) : t] = (red[0] + red[1]) + (red[2] + red[3]);

    p_c = p_n;
    sid_n = sid2;
    dur_c = dur_n;
    dur_n = dur2;
  }
}

__global__ void combine(const float* __restrict__ pf, const float* __restrict__ pb,
                        const float* __restrict__ bd, float* __restrict__ out) {
  const int i = blockIdx.x * blockDim.x + threadIdx.x;
  out[i] = pf[i] + pb[i] + bd[0];
}

extern "C" void kernel_launch(void* const* d_in, const int* in_sizes, int n_in,
                              void* d_out, int out_size, void* d_ws, size_t ws_size,
                              hipStream_t stream) {
  const float* dur = (const float*)d_in[0];
  const int* sid = (const int*)d_in[1];
  const float* embed = (const float*)d_in[2];
  const float* Wi_f = (const float*)d_in[3];
  const float* Wh_f = (const float*)d_in[4];
  const float* bi_f = (const float*)d_in[5];
  const float* bhn_f = (const float*)d_in[6];
  const float* Wi_b = (const float*)d_in[7];
  const float* Wh_b = (const float*)d_in[8];
  const float* bi_b = (const float*)d_in[9];
  const float* bhn_b = (const float*)d_in[10];
  const float* Wd = (const float*)d_in[11];
  const float* bd = (const float*)d_in[12];
  float* out = (float*)d_out;

  // ws layout (floats): [0,65536) fwd partial, [65536,131072) bwd partial,
  // then Pf (1024*768), then Pb (1024*768), then Whp (2*128*768 dwords).
  float* ws = (float*)d_ws;
  float* pf = ws;
  float* pb = ws + 65536;
  float* Pf = ws + 131072;
  float* Pb = Pf + NSING * H3;
  unsigned int* Whp = (unsigned int*)(Pb + NSING * H3);

  hipLaunchKernelGGL(precompute_P, dim3(NSING), dim3(H3), 0, stream, embed, Wi_f, bi_f, Pf);
  hipLaunchKernelGGL(precompute_P, dim3(NSING), dim3(H3), 0, stream, embed, Wi_b, bi_b, Pb);
  hipLaunchKernelGGL(pack_Wh, dim3(256), dim3(H3), 0, stream, Wh_f, Wh_b, Whp);
  hipLaunchKernelGGL(gru_scan, dim3(64), dim3(H3), 0, stream,
                     dur, sid, Whp, Wi_f, Wi_b, bhn_f, bhn_b, Wd, Pf, Pb, ws);
  hipLaunchKernelGGL(combine, dim3(out_size / 256), dim3(256), 0, stream, pf, pb, bd, out);
}